// Round 1
// baseline (1287.794 us; speedup 1.0000x reference)
//
#include <hip/hip_runtime.h>
#include <hip/hip_bf16.h>

#define NB 4096   // B
#define DD 128    // D
#define LL 64     // L
#define GG 8      // G
#define NT 512    // threads per block (8 waves)

__global__ __launch_bounds__(NT) void fused_aggregator_kernel(
    const int* __restrict__ nodes,      // [B,G]
    const int* __restrict__ hu,         // [B,L]
    const int* __restrict__ hr,         // [B,L]
    const int* __restrict__ hlen,       // [B]
    const float* __restrict__ v2e,      // [N_ITEMS, D]
    const float* __restrict__ u2e,      // [N_USERS, D]
    const float* __restrict__ r2e,      // [N_RATINGS, D]
    const float* __restrict__ W1,       // [2D, D]
    const float* __restrict__ b1,       // [D]
    const float* __restrict__ W2,       // [D, D]
    const float* __restrict__ b2,       // [D]
    const float* __restrict__ a1W,      // [2D, D]
    const float* __restrict__ a1b,      // [D]
    const float* __restrict__ a2W,      // [D, D]
    const float* __restrict__ a2b,      // [D]
    const float* __restrict__ a3W,      // [D, 1]
    const float* __restrict__ a3b,      // [1]
    const float* __restrict__ geW,      // [D, D]
    const float* __restrict__ geb,      // [D]
    float* __restrict__ out)            // [B, D]
{
  const int b   = blockIdx.x;
  const int tid = threadIdx.x;
  const int d   = tid & (DD - 1);   // 0..127
  const int lg  = tid >> 7;         // 0..3 : each thread owns 16 l-rows

  // Flat LDS: ecat[64][256] (reused as a1buf[64][128]) | xbuf[64][128] |
  //           obuf[64][128] | gsh[128] | att[64] | wred[8][16] | red[4][128]
  __shared__ float smem[16384 + 8192 + 8192 + 128 + 64 + 128 + 512];
  float* ecat  = smem;                // 16384 floats
  float* a1buf = smem;                // alias (used after ecat is dead)
  float* xbuf  = smem + 16384;        // 8192
  float* obuf  = xbuf + 8192;         // 8192
  float* gsh   = obuf + 8192;         // 128
  float* att_s = gsh + 128;           // 64
  float* wred  = att_s + 64;          // 128 ([8][16])
  float* red   = wred + 128;          // 512 ([4][128]); also mean buffer

  // ---------------- phase 0: gathers ----------------
  if (tid < DD) {
    float acc = 0.f;
    #pragma unroll
    for (int j = 0; j < GG; ++j) {
      int idx = nodes[b * GG + j];
      acc += u2e[(size_t)idx * DD + tid];
    }
    red[tid] = acc * (1.0f / GG);     // members.mean(axis=1)
  }
  for (int idx = tid; idx < LL * 2 * DD; idx += NT) {
    int l = idx >> 8;                 // row of 256
    int k = idx & 255;
    float v;
    if (k < DD) v = v2e[(size_t)hu[b * LL + l] * DD + k];
    else        v = r2e[(size_t)hr[b * LL + l] * DD + (k - DD)];
    ecat[idx] = v;                    // idx == l*256 + k
  }
  __syncthreads();

  // ---------------- phase 1: group rep g (wave0/1) + GEMM1 ----------------
  if (tid < DD) {
    float s = geb[tid];
    #pragma unroll 4
    for (int k = 0; k < DD; ++k) s = fmaf(red[k], geW[k * DD + tid], s);
    gsh[tid] = fmaxf(s, 0.f);
  }

  float acc[16];
  #pragma unroll
  for (int i = 0; i < 16; ++i) acc[i] = 0.f;
  for (int k = 0; k < 2 * DD; k += 4) {
    float w0 = W1[(k + 0) * DD + d];
    float w1 = W1[(k + 1) * DD + d];
    float w2 = W1[(k + 2) * DD + d];
    float w3 = W1[(k + 3) * DD + d];
    #pragma unroll
    for (int i = 0; i < 16; ++i) {
      const float4 e = *reinterpret_cast<const float4*>(&ecat[(lg * 16 + i) * 256 + k]);
      acc[i] = fmaf(e.x, w0, acc[i]);
      acc[i] = fmaf(e.y, w1, acc[i]);
      acc[i] = fmaf(e.z, w2, acc[i]);
      acc[i] = fmaf(e.w, w3, acc[i]);
    }
  }
  {
    float bb = b1[d];
    #pragma unroll
    for (int i = 0; i < 16; ++i)
      xbuf[(lg * 16 + i) * DD + d] = fmaxf(acc[i] + bb, 0.f);
  }
  __syncthreads();

  // ---------------- phase 2: GEMM2 (o) + group-attention bias ----------------
  float gb = a1b[d];
  #pragma unroll 4
  for (int k = 0; k < DD; ++k) gb = fmaf(gsh[k], a1W[(DD + k) * DD + d], gb);

  #pragma unroll
  for (int i = 0; i < 16; ++i) acc[i] = 0.f;
  for (int k = 0; k < DD; k += 4) {
    float w0 = W2[(k + 0) * DD + d];
    float w1 = W2[(k + 1) * DD + d];
    float w2 = W2[(k + 2) * DD + d];
    float w3 = W2[(k + 3) * DD + d];
    #pragma unroll
    for (int i = 0; i < 16; ++i) {
      const float4 x = *reinterpret_cast<const float4*>(&xbuf[(lg * 16 + i) * DD + k]);
      acc[i] = fmaf(x.x, w0, acc[i]);
      acc[i] = fmaf(x.y, w1, acc[i]);
      acc[i] = fmaf(x.z, w2, acc[i]);
      acc[i] = fmaf(x.w, w3, acc[i]);
    }
  }
  {
    float bb = b2[d];
    #pragma unroll
    for (int i = 0; i < 16; ++i)
      obuf[(lg * 16 + i) * DD + d] = fmaxf(acc[i] + bb, 0.f);
  }
  __syncthreads();

  // ---------------- phase 3: GEMM3 (a1 = relu(o@a1W[:D] + gb)) ----------------
  #pragma unroll
  for (int i = 0; i < 16; ++i) acc[i] = 0.f;
  for (int k = 0; k < DD; k += 4) {
    float w0 = a1W[(k + 0) * DD + d];
    float w1 = a1W[(k + 1) * DD + d];
    float w2 = a1W[(k + 2) * DD + d];
    float w3 = a1W[(k + 3) * DD + d];
    #pragma unroll
    for (int i = 0; i < 16; ++i) {
      const float4 o = *reinterpret_cast<const float4*>(&obuf[(lg * 16 + i) * DD + k]);
      acc[i] = fmaf(o.x, w0, acc[i]);
      acc[i] = fmaf(o.y, w1, acc[i]);
      acc[i] = fmaf(o.z, w2, acc[i]);
      acc[i] = fmaf(o.w, w3, acc[i]);
    }
  }
  #pragma unroll
  for (int i = 0; i < 16; ++i)
    a1buf[(lg * 16 + i) * DD + d] = fmaxf(acc[i] + gb, 0.f);
  __syncthreads();

  // ---------------- phase 4: GEMM4 (a2) folded with att3 ----------------
  #pragma unroll
  for (int i = 0; i < 16; ++i) acc[i] = 0.f;
  for (int k = 0; k < DD; k += 4) {
    float w0 = a2W[(k + 0) * DD + d];
    float w1 = a2W[(k + 1) * DD + d];
    float w2 = a2W[(k + 2) * DD + d];
    float w3 = a2W[(k + 3) * DD + d];
    #pragma unroll
    for (int i = 0; i < 16; ++i) {
      const float4 a = *reinterpret_cast<const float4*>(&a1buf[(lg * 16 + i) * DD + k]);
      acc[i] = fmaf(a.x, w0, acc[i]);
      acc[i] = fmaf(a.y, w1, acc[i]);
      acc[i] = fmaf(a.z, w2, acc[i]);
      acc[i] = fmaf(a.w, w3, acc[i]);
    }
  }
  {
    float bb = a2b[d];
    float w3v = a3W[d];
    #pragma unroll
    for (int i = 0; i < 16; ++i)
      acc[i] = fmaxf(acc[i] + bb, 0.f) * w3v;   // a2[l][d] * att3_W[d]
  }
  // reduce over d: 64-lane shuffles, then combine lane0s of wave pairs
  #pragma unroll
  for (int off = 32; off; off >>= 1) {
    #pragma unroll
    for (int i = 0; i < 16; ++i) acc[i] += __shfl_xor(acc[i], off);
  }
  {
    int wv = tid >> 6;                 // 0..7
    if ((tid & 63) == 0) {
      #pragma unroll
      for (int i = 0; i < 16; ++i) wred[wv * 16 + i] = acc[i];
    }
  }
  __syncthreads();

  // ---------------- phase 5: logits + masked softmax (wave 0) ----------------
  if (tid < LL) {
    int l = tid;
    int lg2 = l >> 4, ii = l & 15;
    float lv = wred[(2 * lg2) * 16 + ii] + wred[(2 * lg2 + 1) * 16 + ii] + a3b[0];
    int len = hlen[b] + 1;             // lengths = hist_len + 1, in [1,64]
    if (l >= len) lv = -1e9f;
    float m = lv;
    #pragma unroll
    for (int off = 32; off; off >>= 1) m = fmaxf(m, __shfl_xor(m, off));
    float p = expf(lv - m);
    if (l >= len) p = 0.f;
    float s = p;
    #pragma unroll
    for (int off = 32; off; off >>= 1) s += __shfl_xor(s, off);
    att_s[l] = p / s;
  }
  __syncthreads();

  // ---------------- phase 6: out[b][d] = sum_l att[l]*o[l][d] ----------------
  float part = 0.f;
  #pragma unroll
  for (int i = 0; i < 16; ++i) {
    int l = lg * 16 + i;
    part = fmaf(att_s[l], obuf[l * DD + d], part);
  }
  red[lg * DD + d] = part;
  __syncthreads();
  if (tid < DD) {
    out[(size_t)b * DD + tid] =
        red[0 * DD + tid] + red[1 * DD + tid] + red[2 * DD + tid] + red[3 * DD + tid];
  }
}

extern "C" void kernel_launch(void* const* d_in, const int* in_sizes, int n_in,
                              void* d_out, int out_size, void* d_ws, size_t ws_size,
                              hipStream_t stream) {
  const int*   nodes = (const int*)d_in[0];
  const int*   hu    = (const int*)d_in[1];
  const int*   hr    = (const int*)d_in[2];
  const int*   hlen  = (const int*)d_in[3];
  const float* v2e   = (const float*)d_in[4];
  const float* u2e   = (const float*)d_in[5];
  const float* r2e   = (const float*)d_in[6];
  const float* W1    = (const float*)d_in[7];
  const float* b1    = (const float*)d_in[8];
  const float* W2    = (const float*)d_in[9];
  const float* b2    = (const float*)d_in[10];
  const float* a1W   = (const float*)d_in[11];
  const float* a1b   = (const float*)d_in[12];
  const float* a2W   = (const float*)d_in[13];
  const float* a2b   = (const float*)d_in[14];
  const float* a3W   = (const float*)d_in[15];
  const float* a3b   = (const float*)d_in[16];
  const float* geW   = (const float*)d_in[17];
  const float* geb   = (const float*)d_in[18];
  float* out = (float*)d_out;

  fused_aggregator_kernel<<<NB, NT, 0, stream>>>(
      nodes, hu, hr, hlen, v2e, u2e, r2e,
      W1, b1, W2, b2, a1W, a1b, a2W, a2b, a3W, a3b, geW, geb, out);
}

// Round 2
// 153.451 us; speedup vs baseline: 8.3922x; 8.3922x over previous
//
#include <hip/hip_runtime.h>
#include <hip/hip_bf16.h>

#define DD  128
#define LL  64
#define GG  8
#define NBB 2          // batch rows per main block
#define NT  512        // 8 waves

typedef __attribute__((ext_vector_type(8))) short bf16x8;
typedef __attribute__((ext_vector_type(4))) float f32x4;

// ---- ws layout ----
// bf16 weight tiles, each [128 n][128 k] pre-swizzled LDS image, 32 KB:
//   W1t0 @ ushort ofs 0, W1t1 @ 16384, W2t @ 32768, a1Wt @ 49152, a2Wt @ 65536
// f32 gb[B][128] @ byte ofs 163840
#define WS_GB_BYTES 163840

__device__ inline unsigned short f2bf(float f) {
  unsigned u = __float_as_uint(f);
  unsigned r = (u + 0x7fffu + ((u >> 16) & 1u)) >> 16;   // RNE
  return (unsigned short)r;
}
__device__ inline float bf2f(unsigned short h) {
  return __uint_as_float(((unsigned)h) << 16);
}

// ---------------- pre-kernel 1: weights -> bf16, transposed, pre-swizzled ----------------
__global__ __launch_bounds__(256) void prep_weights(
    const float* __restrict__ W1, const float* __restrict__ W2,
    const float* __restrict__ a1W, const float* __restrict__ a2W,
    unsigned short* __restrict__ wsw) {
  int gid = blockIdx.x * 256 + threadIdx.x;      // 0..10239  (5 tiles x 2048 blocks of 16B)
  int tile = gid >> 11, idx = gid & 2047;
  int row = idx >> 4, slot = idx & 15;
  int slot2 = slot ^ (row & 7);                  // inverse swizzle on source
  const float* W; int kb;
  switch (tile) {
    case 0:  W = W1;  kb = 0;   break;
    case 1:  W = W1;  kb = 128; break;
    case 2:  W = W2;  kb = 0;   break;
    case 3:  W = a1W; kb = 0;   break;
    default: W = a2W; kb = 0;   break;
  }
  unsigned int pk[4];
  #pragma unroll
  for (int p = 0; p < 4; ++p) {
    unsigned short lo = f2bf(W[(size_t)(kb + slot2 * 8 + 2 * p    ) * DD + row]);
    unsigned short hi = f2bf(W[(size_t)(kb + slot2 * 8 + 2 * p + 1) * DD + row]);
    pk[p] = (unsigned)lo | ((unsigned)hi << 16);
  }
  uint4* dst = (uint4*)(wsw + (size_t)tile * 16384 + (size_t)idx * 8);
  *dst = make_uint4(pk[0], pk[1], pk[2], pk[3]);
}

// ---------------- pre-kernel 2: group rep -> folded attention bias gb[b][d] ----------------
__global__ __launch_bounds__(256) void prep_gb(
    const int* __restrict__ nodes, const float* __restrict__ u2e,
    const float* __restrict__ geW, const float* __restrict__ geb,
    const float* __restrict__ a1W, const float* __restrict__ a1b,
    float* __restrict__ gb_out) {
  __shared__ float sgeW[DD * DD];   // 64 KB
  __shared__ float sa1W[DD * DD];   // 64 KB (rows D..2D of a1W)
  __shared__ float smean[2][DD], sg[2][DD];
  int tid = threadIdx.x;
  for (int i = tid; i < DD * DD; i += 256) {
    sgeW[i] = geW[i];
    sa1W[i] = a1W[(size_t)(DD + (i >> 7)) * DD + (i & 127)];
  }
  __syncthreads();
  int b0 = blockIdx.x * 16;
  int sub = tid >> 7, d = tid & 127;
  for (int bi = 0; bi < 16; bi += 2) {
    int b = b0 + bi + sub;
    float m = 0.f;
    #pragma unroll
    for (int j = 0; j < GG; ++j) m += u2e[(size_t)nodes[b * GG + j] * DD + d];
    smean[sub][d] = m * (1.0f / GG);
    __syncthreads();
    float g = geb[d];
    #pragma unroll 4
    for (int k = 0; k < DD; ++k) g = fmaf(smean[sub][k], sgeW[k * DD + d], g);
    sg[sub][d] = fmaxf(g, 0.f);
    __syncthreads();
    float r = a1b[d];
    #pragma unroll 4
    for (int k = 0; k < DD; ++k) r = fmaf(sg[sub][k], sa1W[k * DD + d], r);
    gb_out[(size_t)b * DD + d] = r;
    __syncthreads();
  }
}

// ---------------- main fused kernel ----------------
__device__ inline bf16x8 ldfrag(const char* buf, int rowbase, int kk, int lane) {
  int row = rowbase + (lane & 15);
  int off = (row << 8) + (kk << 6) + (lane & 48);
  off ^= (row & 7) << 4;
  return *(const bf16x8*)(buf + off);
}

__device__ inline void gemm_acc(f32x4 acc[8], const char* A, const char* B,
                                int w, int lane) {
  #pragma unroll
  for (int kk = 0; kk < 4; ++kk) {
    bf16x8 a = ldfrag(A, w * 16, kk, lane);
    #pragma unroll
    for (int ni = 0; ni < 8; ++ni) {
      bf16x8 b = ldfrag(B, ni * 16, kk, lane);
      acc[ni] = __builtin_amdgcn_mfma_f32_16x16x32_bf16(a, b, acc[ni], 0, 0, 0);
    }
  }
}

__device__ inline void cwrite_relu(char* buf, const f32x4 acc[8], const float bias[8],
                                   int w, int lane) {
  int cb = lane & 15, rb = w * 16 + ((lane >> 4) << 2);
  #pragma unroll
  for (int ni = 0; ni < 8; ++ni) {
    int col = ni * 16 + cb;
    #pragma unroll
    for (int j = 0; j < 4; ++j) {
      int row = rb + j;
      float v = fmaxf(acc[ni][j] + bias[ni], 0.f);
      int off = ((row << 8) + (col << 1)) ^ ((row & 7) << 4);
      *(unsigned short*)(buf + off) = f2bf(v);
    }
  }
}

__device__ inline uint4 pack8(float4 a, float4 b) {
  return make_uint4(
      (unsigned)f2bf(a.x) | ((unsigned)f2bf(a.y) << 16),
      (unsigned)f2bf(a.z) | ((unsigned)f2bf(a.w) << 16),
      (unsigned)f2bf(b.x) | ((unsigned)f2bf(b.y) << 16),
      (unsigned)f2bf(b.z) | ((unsigned)f2bf(b.w) << 16));
}

__global__ __launch_bounds__(NT) void main_kernel(
    const int* __restrict__ hu, const int* __restrict__ hr,
    const int* __restrict__ hlen,
    const float* __restrict__ v2e, const float* __restrict__ r2e,
    const float* __restrict__ b1, const float* __restrict__ b2,
    const float* __restrict__ a2b, const float* __restrict__ a3W,
    const float* __restrict__ a3b,
    const unsigned short* __restrict__ wsw,
    const float* __restrict__ gbv,
    float* __restrict__ out) {
  __shared__ char bufA[32768];   // e_uv -> x -> a1
  __shared__ char bufB[32768];   // W1t0 -> W2t -> a2Wt
  __shared__ char bufC[32768];   // e_r  -> o
  __shared__ char bufD[32768];   // W1t1 -> a1Wt
  __shared__ float logit_s[NBB * LL];
  __shared__ float att_s[NBB * LL];
  __shared__ float red_s[2][NBB * DD];

  const int tid = threadIdx.x;
  const int w = tid >> 6;          // wave id == M-tile
  const int lane = tid & 63;
  const int b0 = blockIdx.x * NBB;
  const int cb = lane & 15;

  // ---- P0: stage e_uv->A, e_r->C, W1t0->B, W1t1->D; prefetch W2t -> regs
  uint4 wreg0, wreg1, wreg2, wreg3;
  {
    const uint4* s2 = (const uint4*)(wsw + 32768);  // W2t
    wreg0 = s2[tid];        wreg1 = s2[tid + 512];
    wreg2 = s2[tid + 1024]; wreg3 = s2[tid + 1536];
    const uint4* s0 = (const uint4*)(wsw);          // W1t0
    const uint4* s1 = (const uint4*)(wsw + 16384);  // W1t1
    uint4* d0 = (uint4*)bufB;
    uint4* d1 = (uint4*)bufD;
    #pragma unroll
    for (int i = 0; i < 4; ++i) {
      d0[tid + i * 512] = s0[tid + i * 512];
      d1[tid + i * 512] = s1[tid + i * 512];
    }
    #pragma unroll
    for (int i = 0; i < 4; ++i) {
      int blk = tid + i * 512;            // 0..2047
      int row = blk >> 4, slot = blk & 15;
      int bb = row >> 6, l = row & 63;
      int off = ((row << 8) + (slot << 4)) ^ ((row & 7) << 4);
      {
        int it = hu[(b0 + bb) * LL + l];
        const float4* p = (const float4*)(v2e + (size_t)it * DD + slot * 8);
        *(uint4*)(bufA + off) = pack8(p[0], p[1]);
      }
      {
        int it = hr[(b0 + bb) * LL + l];
        const float4* p = (const float4*)(r2e + (size_t)it * DD + slot * 8);
        *(uint4*)(bufC + off) = pack8(p[0], p[1]);
      }
    }
  }
  __syncthreads();

  f32x4 acc[8];

  // ---- G1: x = relu([e_uv|e_r] @ W1 + b1) -> bufA
  {
    float bias[8];
    #pragma unroll
    for (int ni = 0; ni < 8; ++ni) bias[ni] = b1[ni * 16 + cb];
    #pragma unroll
    for (int i = 0; i < 8; ++i) acc[i] = (f32x4)(0.f);
    gemm_acc(acc, bufA, bufB, w, lane);   // pass a: e_uv @ W1[0:128]
    gemm_acc(acc, bufC, bufD, w, lane);   // pass b: e_r  @ W1[128:256]
    cwrite_relu(bufA, acc, bias, w, lane);  // own-row slice: no cross-wave hazard
  }
  __syncthreads();

  // ---- S1: commit W2t -> bufB; prefetch a1Wt
  {
    uint4* d = (uint4*)bufB;
    d[tid] = wreg0; d[tid + 512] = wreg1; d[tid + 1024] = wreg2; d[tid + 1536] = wreg3;
    const uint4* s = (const uint4*)(wsw + 49152);   // a1Wt
    wreg0 = s[tid];        wreg1 = s[tid + 512];
    wreg2 = s[tid + 1024]; wreg3 = s[tid + 1536];
  }
  __syncthreads();

  // ---- G2: o = relu(x @ W2 + b2) -> bufC
  {
    float bias[8];
    #pragma unroll
    for (int ni = 0; ni < 8; ++ni) bias[ni] = b2[ni * 16 + cb];
    #pragma unroll
    for (int i = 0; i < 8; ++i) acc[i] = (f32x4)(0.f);
    gemm_acc(acc, bufA, bufB, w, lane);
    cwrite_relu(bufC, acc, bias, w, lane);
  }
  __syncthreads();

  // ---- S2: commit a1Wt -> bufD; prefetch a2Wt
  {
    uint4* d = (uint4*)bufD;
    d[tid] = wreg0; d[tid + 512] = wreg1; d[tid + 1024] = wreg2; d[tid + 1536] = wreg3;
    const uint4* s = (const uint4*)(wsw + 65536);   // a2Wt
    wreg0 = s[tid];        wreg1 = s[tid + 512];
    wreg2 = s[tid + 1024]; wreg3 = s[tid + 1536];
  }
  __syncthreads();

  // ---- G3: a1 = relu(o @ a1W[:D] + gb) -> bufA
  {
    float bias[8];
    int bbw = w >> 2;
    #pragma unroll
    for (int ni = 0; ni < 8; ++ni) bias[ni] = gbv[(size_t)(b0 + bbw) * DD + ni * 16 + cb];
    #pragma unroll
    for (int i = 0; i < 8; ++i) acc[i] = (f32x4)(0.f);
    gemm_acc(acc, bufC, bufD, w, lane);
    cwrite_relu(bufA, acc, bias, w, lane);
  }
  __syncthreads();

  // ---- S3: commit a2Wt -> bufB
  {
    uint4* d = (uint4*)bufB;
    d[tid] = wreg0; d[tid + 512] = wreg1; d[tid + 1024] = wreg2; d[tid + 1536] = wreg3;
  }
  __syncthreads();

  // ---- G4: a2 = relu(a1 @ a2W + a2b); logits = a2 @ a3W (reduced in-register)
  {
    float a2breg[8], a3reg[8];
    #pragma unroll
    for (int ni = 0; ni < 8; ++ni) {
      int c = ni * 16 + cb;
      a2breg[ni] = a2b[c];
      a3reg[ni] = a3W[c];
    }
    #pragma unroll
    for (int i = 0; i < 8; ++i) acc[i] = (f32x4)(0.f);
    gemm_acc(acc, bufA, bufB, w, lane);
    float p0 = 0.f, p1 = 0.f, p2 = 0.f, p3 = 0.f;
    #pragma unroll
    for (int ni = 0; ni < 8; ++ni) {
      p0 = fmaf(fmaxf(acc[ni][0] + a2breg[ni], 0.f), a3reg[ni], p0);
      p1 = fmaf(fmaxf(acc[ni][1] + a2breg[ni], 0.f), a3reg[ni], p1);
      p2 = fmaf(fmaxf(acc[ni][2] + a2breg[ni], 0.f), a3reg[ni], p2);
      p3 = fmaf(fmaxf(acc[ni][3] + a2breg[ni], 0.f), a3reg[ni], p3);
    }
    #pragma unroll
    for (int m = 1; m < 16; m <<= 1) {
      p0 += __shfl_xor(p0, m);
      p1 += __shfl_xor(p1, m);
      p2 += __shfl_xor(p2, m);
      p3 += __shfl_xor(p3, m);
    }
    if ((lane & 15) == 0) {
      int rb = w * 16 + ((lane >> 4) << 2);
      logit_s[rb + 0] = p0;
      logit_s[rb + 1] = p1;
      logit_s[rb + 2] = p2;
      logit_s[rb + 3] = p3;
    }
  }
  __syncthreads();

  // ---- P5: masked softmax per bb (waves 0 and 1)
  if (tid < NBB * LL) {
    int row = tid;
    int bb = row >> 6, l = row & 63;
    float lv = logit_s[row] + a3b[0];
    int len = hlen[b0 + bb] + 1;
    bool valid = l < len;
    if (!valid) lv = -1e30f;
    float m = lv;
    #pragma unroll
    for (int off = 32; off; off >>= 1) m = fmaxf(m, __shfl_xor(m, off));
    float p = valid ? expf(lv - m) : 0.f;
    float s = p;
    #pragma unroll
    for (int off = 32; off; off >>= 1) s += __shfl_xor(s, off);
    att_s[row] = p / s;
  }
  __syncthreads();

  // ---- P6: out[bb][d] = sum_l att[l] * o[l][d]
  {
    int d = tid & 127, bb = (tid >> 7) & 1, half = tid >> 8;
    float s = 0.f;
    #pragma unroll 8
    for (int i = 0; i < 32; ++i) {
      int row = bb * 64 + half * 32 + i;
      int off = ((row << 8) + (d << 1)) ^ ((row & 7) << 4);
      s = fmaf(att_s[row], bf2f(*(const unsigned short*)(bufC + off)), s);
    }
    red_s[half][bb * DD + d] = s;
  }
  __syncthreads();
  if (tid < NBB * DD) {
    out[(size_t)b0 * DD + tid] = red_s[0][tid] + red_s[1][tid];
  }
}

extern "C" void kernel_launch(void* const* d_in, const int* in_sizes, int n_in,
                              void* d_out, int out_size, void* d_ws, size_t ws_size,
                              hipStream_t stream) {
  const int*   nodes = (const int*)d_in[0];
  const int*   hu    = (const int*)d_in[1];
  const int*   hr    = (const int*)d_in[2];
  const int*   hlen  = (const int*)d_in[3];
  const float* v2e   = (const float*)d_in[4];
  const float* u2e   = (const float*)d_in[5];
  const float* r2e   = (const float*)d_in[6];
  const float* W1    = (const float*)d_in[7];
  const float* b1    = (const float*)d_in[8];
  const float* W2    = (const float*)d_in[9];
  const float* b2    = (const float*)d_in[10];
  const float* a1W   = (const float*)d_in[11];
  const float* a1b   = (const float*)d_in[12];
  const float* a2W   = (const float*)d_in[13];
  const float* a2b   = (const float*)d_in[14];
  const float* a3W   = (const float*)d_in[15];
  const float* a3b   = (const float*)d_in[16];
  const float* geW   = (const float*)d_in[17];
  const float* geb   = (const float*)d_in[18];
  float* out = (float*)d_out;

  unsigned short* wsw = (unsigned short*)d_ws;
  float* gbv = (float*)((char*)d_ws + WS_GB_BYTES);

  prep_weights<<<40, 256, 0, stream>>>(W1, W2, a1W, a2W, wsw);
  prep_gb<<<256, 256, 0, stream>>>(nodes, u2e, geW, geb, a1W, a1b, gbv);
  main_kernel<<<4096 / NBB, NT, 0, stream>>>(
      hu, hr, hlen, v2e, r2e, b1, b2, a2b, a3W, a3b,
      (const unsigned short*)wsw, (const float*)gbv, out);
}

// Round 3
// 127.484 us; speedup vs baseline: 10.1016x; 1.2037x over previous
//
#include <hip/hip_runtime.h>
#include <hip/hip_bf16.h>

#define DD 128
#define TILE_BYTES 32768
#define WS_R_OFF   196608            // 6 tiles * 32768
#define WS_GB_OFF  199168            // + 640*4 (R')

typedef __attribute__((ext_vector_type(8))) short bf16x8;
typedef __attribute__((ext_vector_type(4))) float f32x4;

__device__ inline unsigned short f2bf(float f) {
  unsigned u = __float_as_uint(f);
  return (unsigned short)((u + 0x7fffu + ((u >> 16) & 1u)) >> 16);   // RNE
}
__device__ inline float bf2f(unsigned short h) {
  return __uint_as_float(((unsigned)h) << 16);
}

// async global->LDS, 16B per lane; LDS dest is wave-uniform base + lane*16
__device__ inline void async16(void* ldsp, const void* gp) {
  __builtin_amdgcn_global_load_lds(
      (const __attribute__((address_space(1))) void*)gp,
      (__attribute__((address_space(3))) void*)ldsp, 16, 0, 0);
}

// fill a 32 KB LDS weight slot from a pre-swizzled global image (linear copy)
__device__ inline void fill_w(char* slot, const char* src, int tid) {
  int w = tid >> 6, lane = tid & 63;
  #pragma unroll
  for (int i = 0; i < 8; ++i) {
    int ofs = ((i << 2) + w) << 10;            // 1 KB per wave-chunk
    async16(slot + ofs, src + ofs + lane * 16);
  }
}

// read a 16x32 bf16 MFMA fragment from a swizzled [rows][128] bf16 tile
__device__ inline bf16x8 ldfrag(const char* buf, int rowbase, int kk, int lane) {
  int row = rowbase + (lane & 15);
  int off = (row << 8) + (kk << 6) + (lane & 48);
  off ^= (row & 7) << 4;
  return *(const bf16x8*)(buf + off);
}

// build an A-fragment directly from a global fp32 row (8 floats -> bf16x8)
__device__ inline bf16x8 ldAg(const float* rp, int kk, int lane) {
  const float4* p = (const float4*)(rp + (kk << 5) + ((lane >> 4) << 3));
  float4 f0 = p[0], f1 = p[1];
  bf16x8 r;
  r[0] = (short)f2bf(f0.x); r[1] = (short)f2bf(f0.y);
  r[2] = (short)f2bf(f0.z); r[3] = (short)f2bf(f0.w);
  r[4] = (short)f2bf(f1.x); r[5] = (short)f2bf(f1.y);
  r[6] = (short)f2bf(f1.z); r[7] = (short)f2bf(f1.w);
  return r;
}

// 32Mx64N wave-tile GEMM step over K=128 (A,B swizzled LDS tiles)
__device__ inline void gemm22(f32x4 acc[8], const char* A, const char* B,
                              int mi, int ni, int lane) {
  #pragma unroll
  for (int kk = 0; kk < 4; ++kk) {
    bf16x8 a0 = ldfrag(A, mi * 32, kk, lane);
    bf16x8 a1 = ldfrag(A, mi * 32 + 16, kk, lane);
    #pragma unroll
    for (int nf = 0; nf < 4; ++nf) {
      bf16x8 b = ldfrag(B, ni * 64 + nf * 16, kk, lane);
      acc[nf]     = __builtin_amdgcn_mfma_f32_16x16x32_bf16(a0, b, acc[nf], 0, 0, 0);
      acc[4 + nf] = __builtin_amdgcn_mfma_f32_16x16x32_bf16(a1, b, acc[4 + nf], 0, 0, 0);
    }
  }
}

__device__ inline void cwrite_col(char* buf, const f32x4 acc[8], const float bias4[4],
                                  int mi, int ni, int lane) {
  int cb = lane & 15, rb = (lane >> 4) << 2;
  #pragma unroll
  for (int mf = 0; mf < 2; ++mf)
    #pragma unroll
    for (int nf = 0; nf < 4; ++nf) {
      int col = ni * 64 + nf * 16 + cb;
      #pragma unroll
      for (int j = 0; j < 4; ++j) {
        int row = mi * 32 + mf * 16 + rb + j;
        float v = fmaxf(acc[mf * 4 + nf][j] + bias4[nf], 0.f);
        int off = ((row << 8) + (col << 1)) ^ ((row & 7) << 4);
        *(unsigned short*)(buf + off) = f2bf(v);
      }
    }
}

// ---------------- pre-kernel 1: weight tiles (bf16, [n][k], pre-swizzled) + R' ----------------
__global__ __launch_bounds__(256) void prep_weights(
    const float* __restrict__ W1, const float* __restrict__ W2,
    const float* __restrict__ a1W, const float* __restrict__ a2W,
    const float* __restrict__ geW,
    const float* __restrict__ r2e, const float* __restrict__ b1,
    unsigned short* __restrict__ wsw, float* __restrict__ Rp) {
  int gid = blockIdx.x * 256 + threadIdx.x;
  if (gid < 12288) {
    int tile = gid >> 11, idx = gid & 2047;
    int row = idx >> 4, slot = idx & 15;
    int slot2 = slot ^ (row & 7);              // inverse swizzle on source
    const float* W; int kb;
    switch (tile) {
      case 0:  W = W1;  kb = 0;   break;       // W1[:128]
      case 1:  W = W2;  kb = 0;   break;
      case 2:  W = a1W; kb = 0;   break;       // a1W[:128]
      case 3:  W = a2W; kb = 0;   break;
      case 4:  W = geW; kb = 0;   break;
      default: W = a1W; kb = 128; break;       // a1W[128:]
    }
    unsigned pk[4];
    #pragma unroll
    for (int p = 0; p < 4; ++p) {
      unsigned short lo = f2bf(W[(size_t)(kb + slot2 * 8 + 2 * p) * DD + row]);
      unsigned short hi = f2bf(W[(size_t)(kb + slot2 * 8 + 2 * p + 1) * DD + row]);
      pk[p] = (unsigned)lo | ((unsigned)hi << 16);
    }
    *(uint4*)(wsw + (size_t)tile * 16384 + (size_t)idx * 8) =
        make_uint4(pk[0], pk[1], pk[2], pk[3]);
  } else {
    // R'[5][128] = r2e @ W1[128:] + b1   (fp32 exact)
    int t = gid - 12288;
    for (int idx = t; idx < 640; idx += 256) {
      int r = idx >> 7, d = idx & 127;
      float s = b1[d];
      for (int k = 0; k < 128; ++k)
        s = fmaf(r2e[r * DD + k], W1[(size_t)(DD + k) * DD + d], s);
      Rp[idx] = s;
    }
  }
}

// ---------------- pre-kernel 2: gb[b][d] = a1b + relu(mean@geW+geb)@a1W[D:] ----------------
__global__ __launch_bounds__(256, 2) void prep_gb(
    const int* __restrict__ nodes, const float* __restrict__ u2e,
    const float* __restrict__ geb, const float* __restrict__ a1b,
    const char* __restrict__ tiles, float* __restrict__ gbv) {
  __shared__ char mean_s[4096];    // [16][128] bf16 swizzled
  __shared__ char g_s[4096];
  __shared__ char wslot[32768];
  __shared__ int nodes_s[128];
  int tid = threadIdx.x, w = tid >> 6, lane = tid & 63;
  int b0 = blockIdx.x * 16;
  if (tid < 128) nodes_s[tid] = nodes[b0 * 8 + tid];
  fill_w(wslot, tiles + 4 * TILE_BYTES, tid);      // geW
  __syncthreads();
  for (int idx = tid; idx < 2048; idx += 256) {
    int row = idx >> 7, d = idx & 127;
    float m = 0.f;
    #pragma unroll
    for (int j = 0; j < 8; ++j)
      m += u2e[(size_t)nodes_s[row * 8 + j] * DD + d];
    m *= 0.125f;
    int off = ((row << 8) + (d << 1)) ^ ((row & 7) << 4);
    *(unsigned short*)(mean_s + off) = f2bf(m);
  }
  __syncthreads();
  int cb = lane & 15, rb = (lane >> 4) << 2;
  f32x4 acc[2] = {(f32x4)(0.f), (f32x4)(0.f)};
  #pragma unroll
  for (int kk = 0; kk < 4; ++kk) {
    bf16x8 a = ldfrag(mean_s, 0, kk, lane);
    #pragma unroll
    for (int nf = 0; nf < 2; ++nf) {
      bf16x8 b = ldfrag(wslot, w * 32 + nf * 16, kk, lane);
      acc[nf] = __builtin_amdgcn_mfma_f32_16x16x32_bf16(a, b, acc[nf], 0, 0, 0);
    }
  }
  __syncthreads();
  fill_w(wslot, tiles + 5 * TILE_BYTES, tid);      // a1W[128:]
  #pragma unroll
  for (int nf = 0; nf < 2; ++nf) {
    int col = w * 32 + nf * 16 + cb;
    float gb2 = geb[col];
    #pragma unroll
    for (int j = 0; j < 4; ++j) {
      int row = rb + j;
      float v = fmaxf(acc[nf][j] + gb2, 0.f);
      int off = ((row << 8) + (col << 1)) ^ ((row & 7) << 4);
      *(unsigned short*)(g_s + off) = f2bf(v);
    }
  }
  __syncthreads();
  acc[0] = (f32x4)(0.f); acc[1] = (f32x4)(0.f);
  #pragma unroll
  for (int kk = 0; kk < 4; ++kk) {
    bf16x8 a = ldfrag(g_s, 0, kk, lane);
    #pragma unroll
    for (int nf = 0; nf < 2; ++nf) {
      bf16x8 b = ldfrag(wslot, w * 32 + nf * 16, kk, lane);
      acc[nf] = __builtin_amdgcn_mfma_f32_16x16x32_bf16(a, b, acc[nf], 0, 0, 0);
    }
  }
  #pragma unroll
  for (int nf = 0; nf < 2; ++nf) {
    int col = w * 32 + nf * 16 + cb;
    float bb = a1b[col];
    #pragma unroll
    for (int j = 0; j < 4; ++j)
      gbv[(size_t)(b0 + rb + j) * DD + col] = acc[nf][j] + bb;
  }
}

// ---------------- main fused kernel: 1 batch row / block, 4 waves ----------------
__global__ __launch_bounds__(256, 2) void main_kernel(
    const int* __restrict__ hu, const int* __restrict__ hr,
    const int* __restrict__ hlen,
    const float* __restrict__ v2e,
    const float* __restrict__ b2, const float* __restrict__ a2b,
    const float* __restrict__ a3W, const float* __restrict__ a3b,
    const char* __restrict__ tiles, const float* __restrict__ Rp,
    const float* __restrict__ gbv, float* __restrict__ out) {
  __shared__ char X[16384];        // x -> a1
  __shared__ char O[16384];        // o
  __shared__ char W[32768];        // rotating weight slot
  __shared__ float R_s[640];
  __shared__ int hu_s[64], hr_s[64];
  __shared__ float lpart[2][64];
  __shared__ float att_s[64];
  __shared__ float red_s[2][128];

  const int tid = threadIdx.x, w = tid >> 6, lane = tid & 63;
  const int mi = w >> 1, ni = w & 1;
  const int cb = lane & 15, rb = (lane >> 4) << 2;
  const int b0 = blockIdx.x;

  fill_w(W, tiles, tid);                          // W1[:128]
  if (tid < 128) {
    int t = tid & 63;
    if (tid < 64) hu_s[t] = hu[b0 * 64 + t];
    else          hr_s[t] = hr[b0 * 64 + t];
  }
  for (int i = tid; i < 640; i += 256) R_s[i] = Rp[i];
  __syncthreads();

  f32x4 acc[8];
  #pragma unroll
  for (int i = 0; i < 8; ++i) acc[i] = (f32x4)(0.f);

  // ---- G1: x = relu(e_uv @ W1[:128] + R'[hr] ) ; A direct from global
  {
    const float* rp0 = v2e + (size_t)hu_s[mi * 32 + cb] * DD;
    const float* rp1 = v2e + (size_t)hu_s[mi * 32 + 16 + cb] * DD;
    #pragma unroll
    for (int kk = 0; kk < 4; ++kk) {
      bf16x8 a0 = ldAg(rp0, kk, lane);
      bf16x8 a1 = ldAg(rp1, kk, lane);
      #pragma unroll
      for (int nf = 0; nf < 4; ++nf) {
        bf16x8 b = ldfrag(W, ni * 64 + nf * 16, kk, lane);
        acc[nf]     = __builtin_amdgcn_mfma_f32_16x16x32_bf16(a0, b, acc[nf], 0, 0, 0);
        acc[4 + nf] = __builtin_amdgcn_mfma_f32_16x16x32_bf16(a1, b, acc[4 + nf], 0, 0, 0);
      }
    }
  }
  __syncthreads();
  fill_w(W, tiles + TILE_BYTES, tid);             // W2
  {
    int rat[2][4];
    #pragma unroll
    for (int mf = 0; mf < 2; ++mf)
      #pragma unroll
      for (int j = 0; j < 4; ++j)
        rat[mf][j] = hr_s[mi * 32 + mf * 16 + rb + j];
    #pragma unroll
    for (int mf = 0; mf < 2; ++mf)
      #pragma unroll
      for (int nf = 0; nf < 4; ++nf) {
        int col = ni * 64 + nf * 16 + cb;
        #pragma unroll
        for (int j = 0; j < 4; ++j) {
          int row = mi * 32 + mf * 16 + rb + j;
          float v = fmaxf(acc[mf * 4 + nf][j] + R_s[rat[mf][j] * DD + col], 0.f);
          int off = ((row << 8) + (col << 1)) ^ ((row & 7) << 4);
          *(unsigned short*)(X + off) = f2bf(v);
        }
      }
  }
  __syncthreads();

  // ---- G2: o = relu(x @ W2 + b2) -> O
  #pragma unroll
  for (int i = 0; i < 8; ++i) acc[i] = (f32x4)(0.f);
  gemm22(acc, X, W, mi, ni, lane);
  __syncthreads();
  fill_w(W, tiles + 2 * TILE_BYTES, tid);         // a1W[:128]
  {
    float bias4[4];
    #pragma unroll
    for (int nf = 0; nf < 4; ++nf) bias4[nf] = b2[ni * 64 + nf * 16 + cb];
    cwrite_col(O, acc, bias4, mi, ni, lane);
  }
  __syncthreads();

  // ---- G3: a1 = relu(o @ a1W[:128] + gb) -> X
  #pragma unroll
  for (int i = 0; i < 8; ++i) acc[i] = (f32x4)(0.f);
  gemm22(acc, O, W, mi, ni, lane);
  __syncthreads();
  fill_w(W, tiles + 3 * TILE_BYTES, tid);         // a2W
  {
    float bias4[4];
    #pragma unroll
    for (int nf = 0; nf < 4; ++nf)
      bias4[nf] = gbv[(size_t)b0 * DD + ni * 64 + nf * 16 + cb];
    cwrite_col(X, acc, bias4, mi, ni, lane);
  }
  __syncthreads();

  // ---- G4: logits = relu(a1 @ a2W + a2b) @ a3W  (in-register reduce)
  #pragma unroll
  for (int i = 0; i < 8; ++i) acc[i] = (f32x4)(0.f);
  gemm22(acc, X, W, mi, ni, lane);
  {
    float a2b4[4], a3w4[4];
    #pragma unroll
    for (int nf = 0; nf < 4; ++nf) {
      int col = ni * 64 + nf * 16 + cb;
      a2b4[nf] = a2b[col];
      a3w4[nf] = a3W[col];
    }
    float p[2][4];
    #pragma unroll
    for (int mf = 0; mf < 2; ++mf)
      #pragma unroll
      for (int j = 0; j < 4; ++j) {
        float s = 0.f;
        #pragma unroll
        for (int nf = 0; nf < 4; ++nf)
          s = fmaf(fmaxf(acc[mf * 4 + nf][j] + a2b4[nf], 0.f), a3w4[nf], s);
        p[mf][j] = s;
      }
    #pragma unroll
    for (int m = 1; m < 16; m <<= 1) {
      #pragma unroll
      for (int mf = 0; mf < 2; ++mf)
        #pragma unroll
        for (int j = 0; j < 4; ++j)
          p[mf][j] += __shfl_xor(p[mf][j], m);
    }
    if (cb == 0) {
      #pragma unroll
      for (int mf = 0; mf < 2; ++mf)
        #pragma unroll
        for (int j = 0; j < 4; ++j)
          lpart[ni][mi * 32 + mf * 16 + rb + j] = p[mf][j];
    }
  }
  __syncthreads();

  // ---- masked softmax over L=64 (wave 0)
  if (tid < 64) {
    float lv = lpart[0][tid] + lpart[1][tid] + a3b[0];
    int len = hlen[b0] + 1;
    bool valid = tid < len;
    if (!valid) lv = -1e30f;
    float m = lv;
    #pragma unroll
    for (int off = 32; off; off >>= 1) m = fmaxf(m, __shfl_xor(m, off));
    float pe = valid ? expf(lv - m) : 0.f;
    float s = pe;
    #pragma unroll
    for (int off = 32; off; off >>= 1) s += __shfl_xor(s, off);
    att_s[tid] = pe / s;
  }
  __syncthreads();

  // ---- out[d] = sum_l att[l] * o[l][d]
  {
    int d = tid & 127, h = tid >> 7;
    float s = 0.f;
    #pragma unroll 8
    for (int i = 0; i < 32; ++i) {
      int r = h * 32 + i;
      int off = ((r << 8) + (d << 1)) ^ ((r & 7) << 4);
      s = fmaf(att_s[r], bf2f(*(const unsigned short*)(O + off)), s);
    }
    red_s[h][d] = s;
  }
  __syncthreads();
  if (tid < 128)
    out[(size_t)b0 * DD + tid] = red_s[0][tid] + red_s[1][tid];
}

extern "C" void kernel_launch(void* const* d_in, const int* in_sizes, int n_in,
                              void* d_out, int out_size, void* d_ws, size_t ws_size,
                              hipStream_t stream) {
  const int*   nodes = (const int*)d_in[0];
  const int*   hu    = (const int*)d_in[1];
  const int*   hr    = (const int*)d_in[2];
  const int*   hlen  = (const int*)d_in[3];
  const float* v2e   = (const float*)d_in[4];
  const float* u2e   = (const float*)d_in[5];
  const float* r2e   = (const float*)d_in[6];
  const float* W1    = (const float*)d_in[7];
  const float* b1    = (const float*)d_in[8];
  const float* W2    = (const float*)d_in[9];
  const float* b2    = (const float*)d_in[10];
  const float* a1W   = (const float*)d_in[11];
  const float* a1b   = (const float*)d_in[12];
  const float* a2W   = (const float*)d_in[13];
  const float* a2b   = (const float*)d_in[14];
  const float* a3W   = (const float*)d_in[15];
  const float* a3b   = (const float*)d_in[16];
  const float* geW   = (const float*)d_in[17];
  const float* geb   = (const float*)d_in[18];
  float* out = (float*)d_out;

  unsigned short* wsw = (unsigned short*)d_ws;
  const char* tiles = (const char*)d_ws;
  float* Rp  = (float*)((char*)d_ws + WS_R_OFF);
  float* gbv = (float*)((char*)d_ws + WS_GB_OFF);

  prep_weights<<<49, 256, 0, stream>>>(W1, W2, a1W, a2W, geW, r2e, b1, wsw, Rp);
  prep_gb<<<256, 256, 0, stream>>>(nodes, u2e, geb, a1b, tiles, gbv);
  main_kernel<<<4096, 256, 0, stream>>>(
      hu, hr, hlen, v2e, b2, a2b, a3W, a3b, tiles, Rp, gbv, out);
}

// Round 4
// 111.189 us; speedup vs baseline: 11.5821x; 1.1466x over previous
//
#include <hip/hip_runtime.h>
#include <hip/hip_bf16.h>

#define DD 128
#define TILE_BYTES 32768
#define WS_R_OFF   196608            // 6 tiles * 32768
#define WS_GB_OFF  199168            // + 640*4 (R')

typedef __attribute__((ext_vector_type(8))) short bf16x8;
typedef __attribute__((ext_vector_type(4))) float f32x4;

__device__ inline unsigned short f2bf(float f) {
  unsigned u = __float_as_uint(f);
  return (unsigned short)((u + 0x7fffu + ((u >> 16) & 1u)) >> 16);   // RNE
}

// async global->LDS, 16B per lane; LDS dest is wave-uniform base + lane*16
__device__ inline void async16(void* ldsp, const void* gp) {
  __builtin_amdgcn_global_load_lds(
      (const __attribute__((address_space(1))) void*)gp,
      (__attribute__((address_space(3))) void*)ldsp, 16, 0, 0);
}

// fill a 32 KB LDS weight slot from a pre-swizzled global image (linear copy)
__device__ inline void fill_w(char* slot, const char* src, int tid) {
  int w = tid >> 6, lane = tid & 63;
  #pragma unroll
  for (int i = 0; i < 8; ++i) {
    int ofs = ((i << 2) + w) << 10;            // 1 KB per wave-chunk
    async16(slot + ofs, src + ofs + lane * 16);
  }
}

// read a 16x32 bf16 MFMA fragment from a swizzled [rows][128] bf16 tile
__device__ inline bf16x8 ldfrag(const char* buf, int rowbase, int kk, int lane) {
  int row = rowbase + (lane & 15);
  int off = (row << 8) + (kk << 6) + (lane & 48);
  off ^= (row & 7) << 4;
  return *(const bf16x8*)(buf + off);
}

// build a fragment directly from a global fp32 row (8 floats -> bf16x8)
__device__ inline bf16x8 ldAg(const float* rp, int kk, int lane) {
  const float4* p = (const float4*)(rp + (kk << 5) + ((lane >> 4) << 3));
  float4 f0 = p[0], f1 = p[1];
  bf16x8 r;
  r[0] = (short)f2bf(f0.x); r[1] = (short)f2bf(f0.y);
  r[2] = (short)f2bf(f0.z); r[3] = (short)f2bf(f0.w);
  r[4] = (short)f2bf(f1.x); r[5] = (short)f2bf(f1.y);
  r[6] = (short)f2bf(f1.z); r[7] = (short)f2bf(f1.w);
  return r;
}

__device__ inline uint2 pack4(float v0, float v1, float v2, float v3) {
  return make_uint2((unsigned)f2bf(v0) | ((unsigned)f2bf(v1) << 16),
                    (unsigned)f2bf(v2) | ((unsigned)f2bf(v3) << 16));
}

#define MFMA(a, b, c) __builtin_amdgcn_mfma_f32_16x16x32_bf16((a), (b), (c), 0, 0, 0)

// ---------------- pre-kernel 1: weight tiles (bf16, [n][k], pre-swizzled) + R' ----------------
__global__ __launch_bounds__(256) void prep_weights(
    const float* __restrict__ W1, const float* __restrict__ W2,
    const float* __restrict__ a1W, const float* __restrict__ a2W,
    const float* __restrict__ geW,
    const float* __restrict__ r2e, const float* __restrict__ b1,
    unsigned short* __restrict__ wsw, float* __restrict__ Rp) {
  int gid = blockIdx.x * 256 + threadIdx.x;
  if (gid < 12288) {
    int tile = gid >> 11, idx = gid & 2047;
    int row = idx >> 4, slot = idx & 15;
    int slot2 = slot ^ (row & 7);              // inverse swizzle on source
    const float* W; int kb;
    switch (tile) {
      case 0:  W = W1;  kb = 0;   break;       // W1[:128]
      case 1:  W = W2;  kb = 0;   break;
      case 2:  W = a1W; kb = 0;   break;       // a1W[:128]
      case 3:  W = a2W; kb = 0;   break;
      case 4:  W = geW; kb = 0;   break;
      default: W = a1W; kb = 128; break;       // a1W[128:]
    }
    unsigned pk[4];
    #pragma unroll
    for (int p = 0; p < 4; ++p) {
      unsigned short lo = f2bf(W[(size_t)(kb + slot2 * 8 + 2 * p) * DD + row]);
      unsigned short hi = f2bf(W[(size_t)(kb + slot2 * 8 + 2 * p + 1) * DD + row]);
      pk[p] = (unsigned)lo | ((unsigned)hi << 16);
    }
    *(uint4*)(wsw + (size_t)tile * 16384 + (size_t)idx * 8) =
        make_uint4(pk[0], pk[1], pk[2], pk[3]);
  } else {
    // R'[5][128] = r2e @ W1[128:] + b1   (fp32 exact)
    int t = gid - 12288;
    for (int idx = t; idx < 640; idx += 256) {
      int r = idx >> 7, d = idx & 127;
      float s = b1[d];
      for (int k = 0; k < 128; ++k)
        s = fmaf(r2e[r * DD + k], W1[(size_t)(DD + k) * DD + d], s);
      Rp[idx] = s;
    }
  }
}

// ---------------- pre-kernel 2: gb[b][d] = a1b + relu(mean@geW+geb)@a1W[D:] ----------------
__global__ __launch_bounds__(256, 2) void prep_gb(
    const int* __restrict__ nodes, const float* __restrict__ u2e,
    const float* __restrict__ geb, const float* __restrict__ a1b,
    const char* __restrict__ tiles, float* __restrict__ gbv) {
  __shared__ char mean_s[4096];    // [16][128] bf16 swizzled
  __shared__ char g_s[4096];
  __shared__ char wslot[32768];
  __shared__ int nodes_s[128];
  int tid = threadIdx.x, w = tid >> 6, lane = tid & 63;
  int b0 = blockIdx.x * 16;
  if (tid < 128) nodes_s[tid] = nodes[b0 * 8 + tid];
  fill_w(wslot, tiles + 4 * TILE_BYTES, tid);      // geW
  __syncthreads();
  for (int idx = tid; idx < 2048; idx += 256) {
    int row = idx >> 7, d = idx & 127;
    float m = 0.f;
    #pragma unroll
    for (int j = 0; j < 8; ++j)
      m += u2e[(size_t)nodes_s[row * 8 + j] * DD + d];
    m *= 0.125f;
    int off = ((row << 8) + (d << 1)) ^ ((row & 7) << 4);
    *(unsigned short*)(mean_s + off) = f2bf(m);
  }
  __syncthreads();
  int cb = lane & 15, rb = (lane >> 4) << 2;
  f32x4 acc[2] = {(f32x4)(0.f), (f32x4)(0.f)};
  #pragma unroll
  for (int kk = 0; kk < 4; ++kk) {
    bf16x8 a = ldfrag(mean_s, 0, kk, lane);
    #pragma unroll
    for (int nf = 0; nf < 2; ++nf) {
      bf16x8 b = ldfrag(wslot, w * 32 + nf * 16, kk, lane);
      acc[nf] = MFMA(a, b, acc[nf]);
    }
  }
  __syncthreads();
  fill_w(wslot, tiles + 5 * TILE_BYTES, tid);      // a1W[128:]
  #pragma unroll
  for (int nf = 0; nf < 2; ++nf) {
    int col = w * 32 + nf * 16 + cb;
    float gb2 = geb[col];
    #pragma unroll
    for (int j = 0; j < 4; ++j) {
      int row = rb + j;
      float v = fmaxf(acc[nf][j] + gb2, 0.f);
      int off = ((row << 8) + (col << 1)) ^ ((row & 7) << 4);
      *(unsigned short*)(g_s + off) = f2bf(v);
    }
  }
  __syncthreads();
  acc[0] = (f32x4)(0.f); acc[1] = (f32x4)(0.f);
  #pragma unroll
  for (int kk = 0; kk < 4; ++kk) {
    bf16x8 a = ldfrag(g_s, 0, kk, lane);
    #pragma unroll
    for (int nf = 0; nf < 2; ++nf) {
      bf16x8 b = ldfrag(wslot, w * 32 + nf * 16, kk, lane);
      acc[nf] = MFMA(a, b, acc[nf]);
    }
  }
  #pragma unroll
  for (int nf = 0; nf < 2; ++nf) {
    int col = w * 32 + nf * 16 + cb;
    float bb = a1b[col];
    #pragma unroll
    for (int j = 0; j < 4; ++j)
      gbv[(size_t)(b0 + rb + j) * DD + col] = acc[nf][j] + bb;
  }
}

// ---------------- main: swapped-operand fused chain, 1 row/block, 4 waves ----------------
// D[f,l] = mfma(A=W[f][k], B=act[l][k]); lane holds l=lane&15, f=(lane>>4)*4+j.
__device__ inline void gemmWX(f32x4 acc[8], const char* Wt, const char* Xt,
                              int mfw, int nlw, int lane) {
  #pragma unroll
  for (int kk = 0; kk < 4; ++kk) {
    bf16x8 bf0 = ldfrag(Xt, nlw * 32, kk, lane);
    bf16x8 bf1 = ldfrag(Xt, nlw * 32 + 16, kk, lane);
    #pragma unroll
    for (int mf = 0; mf < 4; ++mf) {
      bf16x8 a = ldfrag(Wt, mfw * 64 + mf * 16, kk, lane);
      acc[mf * 2]     = MFMA(a, bf0, acc[mf * 2]);
      acc[mf * 2 + 1] = MFMA(a, bf1, acc[mf * 2 + 1]);
    }
  }
}

__global__ __launch_bounds__(256, 3) void main_kernel(
    const int* __restrict__ hu, const int* __restrict__ hr,
    const int* __restrict__ hlen,
    const float* __restrict__ v2e,
    const float* __restrict__ b2, const float* __restrict__ a2b,
    const float* __restrict__ a3W, const float* __restrict__ a3b,
    const char* __restrict__ tiles, const float* __restrict__ Rp,
    const float* __restrict__ gbv, float* __restrict__ out) {
  __shared__ char W[32768];        // rotating weight slot: W1 -> W2 -> a1W -> a2W
  __shared__ char X[16384];        // x -> o -> a1 (in-place, barrier-separated)
  __shared__ float lpart[2][64];
  __shared__ float att_s[64];
  __shared__ float red_s[2][128];

  const int tid = threadIdx.x, lane = tid & 63;
  const int wv = tid >> 6;
  const int mfw = wv >> 1, nlw = wv & 1;   // wave tile: f in [mfw*64,+64), l in [nlw*32,+32)
  const int cb = lane & 15, g = lane >> 4;
  const int b0 = blockIdx.x;

  fill_w(W, tiles, tid);                           // W1[:128]
  const int l0 = nlw * 32 + cb, l1 = l0 + 16;
  const int hu0 = hu[b0 * 64 + l0], hu1 = hu[b0 * 64 + l1];
  const int hr0 = hr[b0 * 64 + l0], hr1 = hr[b0 * 64 + l1];
  __syncthreads();

  f32x4 acc[8];
  #pragma unroll
  for (int i = 0; i < 8; ++i) acc[i] = (f32x4)(0.f);

  // ---- G1: x[f,l] = e_uv[l] @ W1[:128];  B built from global v2e rows
  {
    const float* rp0 = v2e + (size_t)hu0 * DD;
    const float* rp1 = v2e + (size_t)hu1 * DD;
    #pragma unroll
    for (int kk = 0; kk < 4; ++kk) {
      bf16x8 bf0 = ldAg(rp0, kk, lane);
      bf16x8 bf1 = ldAg(rp1, kk, lane);
      #pragma unroll
      for (int mf = 0; mf < 4; ++mf) {
        bf16x8 a = ldfrag(W, mfw * 64 + mf * 16, kk, lane);
        acc[mf * 2]     = MFMA(a, bf0, acc[mf * 2]);
        acc[mf * 2 + 1] = MFMA(a, bf1, acc[mf * 2 + 1]);
      }
    }
  }
  __syncthreads();                                  // done reading W1
  fill_w(W, tiles + TILE_BYTES, tid);               // W2
  #pragma unroll
  for (int mf = 0; mf < 4; ++mf) {                  // epi1: +R'[hr], relu, b64 write
    int f0 = mfw * 64 + mf * 16 + g * 4;
    float4 r0 = *(const float4*)(Rp + hr0 * DD + f0);
    float4 r1 = *(const float4*)(Rp + hr1 * DD + f0);
    f32x4 v0 = acc[mf * 2], v1 = acc[mf * 2 + 1];
    uint2 p0 = pack4(fmaxf(v0[0] + r0.x, 0.f), fmaxf(v0[1] + r0.y, 0.f),
                     fmaxf(v0[2] + r0.z, 0.f), fmaxf(v0[3] + r0.w, 0.f));
    uint2 p1 = pack4(fmaxf(v1[0] + r1.x, 0.f), fmaxf(v1[1] + r1.y, 0.f),
                     fmaxf(v1[2] + r1.z, 0.f), fmaxf(v1[3] + r1.w, 0.f));
    int o0 = ((l0 << 8) + (f0 << 1)) ^ ((l0 & 7) << 4);
    int o1 = ((l1 << 8) + (f0 << 1)) ^ ((l1 & 7) << 4);
    *(uint2*)(X + o0) = p0;
    *(uint2*)(X + o1) = p1;
  }
  __syncthreads();                                  // x ready, W2 ready

  // ---- G2: o = relu(x @ W2 + b2); keep packed o in regs
  #pragma unroll
  for (int i = 0; i < 8; ++i) acc[i] = (f32x4)(0.f);
  gemmWX(acc, W, X, mfw, nlw, lane);
  __syncthreads();                                  // done reading x, W2
  fill_w(W, tiles + 2 * TILE_BYTES, tid);           // a1W[:128]
  uint2 opk[8];
  #pragma unroll
  for (int mf = 0; mf < 4; ++mf) {
    int f0 = mfw * 64 + mf * 16 + g * 4;
    float4 bb = *(const float4*)(b2 + f0);
    f32x4 v0 = acc[mf * 2], v1 = acc[mf * 2 + 1];
    uint2 p0 = pack4(fmaxf(v0[0] + bb.x, 0.f), fmaxf(v0[1] + bb.y, 0.f),
                     fmaxf(v0[2] + bb.z, 0.f), fmaxf(v0[3] + bb.w, 0.f));
    uint2 p1 = pack4(fmaxf(v1[0] + bb.x, 0.f), fmaxf(v1[1] + bb.y, 0.f),
                     fmaxf(v1[2] + bb.z, 0.f), fmaxf(v1[3] + bb.w, 0.f));
    opk[mf * 2] = p0; opk[mf * 2 + 1] = p1;
    int o0 = ((l0 << 8) + (f0 << 1)) ^ ((l0 & 7) << 4);
    int o1 = ((l1 << 8) + (f0 << 1)) ^ ((l1 & 7) << 4);
    *(uint2*)(X + o0) = p0;
    *(uint2*)(X + o1) = p1;
  }
  __syncthreads();                                  // o ready, a1W ready

  // ---- G3: a1 = relu(o @ a1W[:128] + gb)
  #pragma unroll
  for (int i = 0; i < 8; ++i) acc[i] = (f32x4)(0.f);
  gemmWX(acc, W, X, mfw, nlw, lane);
  __syncthreads();                                  // done reading o, a1W
  fill_w(W, tiles + 3 * TILE_BYTES, tid);           // a2W
  #pragma unroll
  for (int mf = 0; mf < 4; ++mf) {
    int f0 = mfw * 64 + mf * 16 + g * 4;
    float4 gg = *(const float4*)(gbv + (size_t)b0 * DD + f0);
    f32x4 v0 = acc[mf * 2], v1 = acc[mf * 2 + 1];
    uint2 p0 = pack4(fmaxf(v0[0] + gg.x, 0.f), fmaxf(v0[1] + gg.y, 0.f),
                     fmaxf(v0[2] + gg.z, 0.f), fmaxf(v0[3] + gg.w, 0.f));
    uint2 p1 = pack4(fmaxf(v1[0] + gg.x, 0.f), fmaxf(v1[1] + gg.y, 0.f),
                     fmaxf(v1[2] + gg.z, 0.f), fmaxf(v1[3] + gg.w, 0.f));
    int o0 = ((l0 << 8) + (f0 << 1)) ^ ((l0 & 7) << 4);
    int o1 = ((l1 << 8) + (f0 << 1)) ^ ((l1 & 7) << 4);
    *(uint2*)(X + o0) = p0;
    *(uint2*)(X + o1) = p1;
  }
  __syncthreads();                                  // a1 ready, a2W ready

  // ---- G4: logits[l] = sum_f relu(a1 @ a2W + a2b)[f,l] * a3W[f]
  #pragma unroll
  for (int i = 0; i < 8; ++i) acc[i] = (f32x4)(0.f);
  gemmWX(acc, W, X, mfw, nlw, lane);
  {
    float s0 = 0.f, s1 = 0.f;
    #pragma unroll
    for (int mf = 0; mf < 4; ++mf) {
      int f0 = mfw * 64 + mf * 16 + g * 4;
      float4 ab = *(const float4*)(a2b + f0);
      float4 aw = *(const float4*)(a3W + f0);
      f32x4 v0 = acc[mf * 2], v1 = acc[mf * 2 + 1];
      s0 = fmaf(fmaxf(v0[0] + ab.x, 0.f), aw.x, s0);
      s0 = fmaf(fmaxf(v0[1] + ab.y, 0.f), aw.y, s0);
      s0 = fmaf(fmaxf(v0[2] + ab.z, 0.f), aw.z, s0);
      s0 = fmaf(fmaxf(v0[3] + ab.w, 0.f), aw.w, s0);
      s1 = fmaf(fmaxf(v1[0] + ab.x, 0.f), aw.x, s1);
      s1 = fmaf(fmaxf(v1[1] + ab.y, 0.f), aw.y, s1);
      s1 = fmaf(fmaxf(v1[2] + ab.z, 0.f), aw.z, s1);
      s1 = fmaf(fmaxf(v1[3] + ab.w, 0.f), aw.w, s1);
    }
    s0 += __shfl_xor(s0, 16); s0 += __shfl_xor(s0, 32);
    s1 += __shfl_xor(s1, 16); s1 += __shfl_xor(s1, 32);
    if (g == 0) { lpart[mfw][l0] = s0; lpart[mfw][l1] = s1; }
  }
  __syncthreads();

  // ---- masked softmax over L=64 (wave 0)
  if (tid < 64) {
    float lv = lpart[0][tid] + lpart[1][tid] + a3b[0];
    int len = hlen[b0] + 1;
    bool valid = tid < len;
    if (!valid) lv = -1e30f;
    float m = lv;
    #pragma unroll
    for (int off = 32; off; off >>= 1) m = fmaxf(m, __shfl_xor(m, off));
    float pe = valid ? expf(lv - m) : 0.f;
    float s = pe;
    #pragma unroll
    for (int off = 32; off; off >>= 1) s += __shfl_xor(s, off);
    att_s[tid] = pe / s;
  }
  __syncthreads();

  // ---- out[d] = sum_l att[l] * o[l][d]  from register copy opk
  {
    float att0 = att_s[l0], att1 = att_s[l1];
    float p[4][4];
    #pragma unroll
    for (int mf = 0; mf < 4; ++mf) {
      uint2 q0 = opk[mf * 2], q1 = opk[mf * 2 + 1];
      p[mf][0] = att0 * __uint_as_float(q0.x << 16)
               + att1 * __uint_as_float(q1.x << 16);
      p[mf][1] = att0 * __uint_as_float(q0.x & 0xffff0000u)
               + att1 * __uint_as_float(q1.x & 0xffff0000u);
      p[mf][2] = att0 * __uint_as_float(q0.y << 16)
               + att1 * __uint_as_float(q1.y << 16);
      p[mf][3] = att0 * __uint_as_float(q0.y & 0xffff0000u)
               + att1 * __uint_as_float(q1.y & 0xffff0000u);
    }
    #pragma unroll
    for (int m = 1; m < 16; m <<= 1) {
      #pragma unroll
      for (int mf = 0; mf < 4; ++mf) {
        p[mf][0] += __shfl_xor(p[mf][0], m);
        p[mf][1] += __shfl_xor(p[mf][1], m);
        p[mf][2] += __shfl_xor(p[mf][2], m);
        p[mf][3] += __shfl_xor(p[mf][3], m);
      }
    }
    if (cb == 0) {
      #pragma unroll
      for (int mf = 0; mf < 4; ++mf) {
        int d = mfw * 64 + mf * 16 + g * 4;
        red_s[nlw][d + 0] = p[mf][0];
        red_s[nlw][d + 1] = p[mf][1];
        red_s[nlw][d + 2] = p[mf][2];
        red_s[nlw][d + 3] = p[mf][3];
      }
    }
  }
  __syncthreads();
  if (tid < 128)
    out[(size_t)b0 * DD + tid] = red_s[0][tid] + red_s[1][tid];
}

extern "C" void kernel_launch(void* const* d_in, const int* in_sizes, int n_in,
                              void* d_out, int out_size, void* d_ws, size_t ws_size,
                              hipStream_t stream) {
  const int*   nodes = (const int*)d_in[0];
  const int*   hu    = (const int*)d_in[1];
  const int*   hr    = (const int*)d_in[2];
  const int*   hlen  = (const int*)d_in[3];
  const float* v2e   = (const float*)d_in[4];
  const float* u2e   = (const float*)d_in[5];
  const float* r2e   = (const float*)d_in[6];
  const float* W1    = (const float*)d_in[7];
  const float* b1    = (const float*)d_in[8];
  const float* W2    = (const float*)d_in[9];
  const float* b2    = (const float*)d_in[10];
  const float* a1W   = (const float*)d_in[11];
  const float* a1b   = (const float*)d_in[12];
  const float* a2W   = (const float*)d_in[13];
  const float* a2b   = (const float*)d_in[14];
  const float* a3W   = (const float*)d_in[15];
  const float* a3b   = (const float*)d_in[16];
  const float* geW   = (const float*)d_in[17];
  const float* geb   = (const float*)d_in[18];
  float* out = (float*)d_out;

  unsigned short* wsw = (unsigned short*)d_ws;
  const char* tiles = (const char*)d_ws;
  float* Rp  = (float*)((char*)d_ws + WS_R_OFF);
  float* gbv = (float*)((char*)d_ws + WS_GB_OFF);

  prep_weights<<<49, 256, 0, stream>>>(W1, W2, a1W, a2W, geW, r2e, b1, wsw, Rp);
  prep_gb<<<256, 256, 0, stream>>>(nodes, u2e, geb, a1b, tiles, gbv);
  main_kernel<<<4096, 256, 0, stream>>>(
      hu, hr, hlen, v2e, b2, a2b, a3W, a3b, tiles, Rp, gbv, out);
}